// Round 1
// baseline (662.251 us; speedup 1.0000x reference)
//
#include <hip/hip_runtime.h>
#include <math.h>

#define D 128

// ---------------------------------------------------------------- utilities

__global__ void zero_i32_kernel(int* __restrict__ p, int n) {
    int i = blockIdx.x * blockDim.x + threadIdx.x;
    if (i < n) p[i] = 0;
}

// ---------------------------------------------------------------- CSR build

__global__ void count_deg_kernel(const int* __restrict__ dst, int* __restrict__ deg, int E) {
    int e = blockIdx.x * blockDim.x + threadIdx.x;
    if (e < E) atomicAdd(&deg[dst[e]], 1);
}

__global__ __launch_bounds__(1024)
void scan_kernel(const int* __restrict__ deg, int* __restrict__ row_ptr,
                 int* __restrict__ fill_ptr, int n) {
    __shared__ int sums[1024];
    int t = threadIdx.x;
    int per = (n + 1023) / 1024;
    int beg = t * per, end = min(n, beg + per);
    int s = 0;
    for (int i = beg; i < end; ++i) s += deg[i];
    sums[t] = s;
    __syncthreads();
    // Hillis-Steele inclusive scan
    for (int off = 1; off < 1024; off <<= 1) {
        int v = (t >= off) ? sums[t - off] : 0;
        __syncthreads();
        sums[t] += v;
        __syncthreads();
    }
    if (t == 1023) row_ptr[n] = sums[1023];
    int prefix = (t > 0) ? sums[t - 1] : 0;
    for (int i = beg; i < end; ++i) {
        row_ptr[i] = prefix;
        fill_ptr[i] = prefix;
        prefix += deg[i];
    }
}

__global__ void fill_csr_kernel(const int* __restrict__ src, const int* __restrict__ dst,
                                int* __restrict__ fill_ptr, int* __restrict__ csr_src, int E) {
    int e = blockIdx.x * blockDim.x + threadIdx.x;
    if (e < E) {
        int p = atomicAdd(&fill_ptr[dst[e]], 1);
        csr_src[p] = src[e];
    }
}

// ---------------------------------------------------------------- f32 GEMM
// C[M,128] = X[M,128] @ W[128,128] + bias.  blockIdx.y selects one of up to
// 4 (W,bias,C) triples so a whole layer's A/B/D/E projections are one launch.
// Block 256 threads, output tile 64x128, per-thread 4x8, BK=32 LDS-staged.

__global__ __launch_bounds__(256)
void gemm4_kernel(const float* __restrict__ X,
                  const float* __restrict__ W0, const float* __restrict__ B0, float* __restrict__ C0,
                  const float* __restrict__ W1, const float* __restrict__ B1, float* __restrict__ C1,
                  const float* __restrict__ W2, const float* __restrict__ B2, float* __restrict__ C2,
                  const float* __restrict__ W3, const float* __restrict__ B3, float* __restrict__ C3,
                  int M) {
    const float* W; const float* Bv; float* C;
    switch (blockIdx.y) {
        case 0:  W = W0; Bv = B0; C = C0; break;
        case 1:  W = W1; Bv = B1; C = C1; break;
        case 2:  W = W2; Bv = B2; C = C2; break;
        default: W = W3; Bv = B3; C = C3; break;
    }
    __shared__ float Xs[32 * 68];    // k-major (transposed), stride 68 breaks bank conflicts
    __shared__ float Ws[32 * 128];   // row-major chunk

    const int tid = threadIdx.x;
    const int m0  = blockIdx.x * 64;
    const int tn  = tid & 15, tm = tid >> 4;
    const int c0  = tn * 8,  r0 = tm * 4;

    float acc[4][8];
    #pragma unroll
    for (int i = 0; i < 4; ++i)
        #pragma unroll
        for (int j = 0; j < 8; ++j) acc[i][j] = 0.f;

    const int cg   = tid & 7;   // which 4-wide k group this thread stages
    const int xrow = tid >> 3;  // 0..31

    for (int k0 = 0; k0 < 128; k0 += 32) {
        // stage X tile (transposed into Xs[k][m])
        #pragma unroll
        for (int b = 0; b < 2; ++b) {
            int row = xrow + b * 32;
            int m = m0 + row;
            float4 v = make_float4(0.f, 0.f, 0.f, 0.f);
            if (m < M) v = *(const float4*)(X + (size_t)m * D + k0 + cg * 4);
            Xs[(cg * 4 + 0) * 68 + row] = v.x;
            Xs[(cg * 4 + 1) * 68 + row] = v.y;
            Xs[(cg * 4 + 2) * 68 + row] = v.z;
            Xs[(cg * 4 + 3) * 68 + row] = v.w;
        }
        // stage W rows k0..k0+31 (contiguous 16KB)
        {
            const float4* Wsrc = (const float4*)(W + (size_t)k0 * D);
            float4* Wdst = (float4*)Ws;
            #pragma unroll
            for (int i = 0; i < 4; ++i) Wdst[i * 256 + tid] = Wsrc[i * 256 + tid];
        }
        __syncthreads();
        #pragma unroll
        for (int k = 0; k < 32; ++k) {
            float4 xv = *(const float4*)(Xs + k * 68 + r0);
            float4 wa = *(const float4*)(Ws + k * 128 + c0);
            float4 wb = *(const float4*)(Ws + k * 128 + c0 + 4);
            float xs[4]  = {xv.x, xv.y, xv.z, xv.w};
            float wsv[8] = {wa.x, wa.y, wa.z, wa.w, wb.x, wb.y, wb.z, wb.w};
            #pragma unroll
            for (int i = 0; i < 4; ++i)
                #pragma unroll
                for (int j = 0; j < 8; ++j) acc[i][j] = fmaf(xs[i], wsv[j], acc[i][j]);
        }
        __syncthreads();
    }

    float bia[8];
    #pragma unroll
    for (int j = 0; j < 8; ++j) bia[j] = Bv[c0 + j];
    #pragma unroll
    for (int i = 0; i < 4; ++i) {
        int m = m0 + r0 + i;
        if (m < M) {
            float4 oa, ob;
            oa.x = acc[i][0] + bia[0]; oa.y = acc[i][1] + bia[1];
            oa.z = acc[i][2] + bia[2]; oa.w = acc[i][3] + bia[3];
            ob.x = acc[i][4] + bia[4]; ob.y = acc[i][5] + bia[5];
            ob.z = acc[i][6] + bia[6]; ob.w = acc[i][7] + bia[7];
            *(float4*)(C + (size_t)m * D + c0)     = oa;
            *(float4*)(C + (size_t)m * D + c0 + 4) = ob;
        }
    }
}

// ---------------------------------------------------------------- aggregation
// One block (128 threads = feature dim) per dst node. num/den in registers,
// no atomics. Edge src lists come from the per-call CSR.

__global__ __launch_bounds__(128)
void aggregate_kernel(const float* __restrict__ Ah, const float* __restrict__ Bh,
                      const float* __restrict__ Dh, const float* __restrict__ Eh,
                      const int* __restrict__ row_ptr, const int* __restrict__ csr_src,
                      float* __restrict__ tmp) {
    const int node = blockIdx.x;
    const int d = threadIdx.x;
    const float dh = Dh[(size_t)node * D + d];
    float num = 0.f, den = 0.f;
    const int beg = row_ptr[node], end = row_ptr[node + 1];
    __shared__ int s_src[128];
    for (int base = beg; base < end; base += 128) {
        int cnt = min(128, end - base);
        __syncthreads();
        if (d < cnt) s_src[d] = csr_src[base + d];
        __syncthreads();
        for (int i = 0; i < cnt; ++i) {
            int s = s_src[i];
            float e = Eh[(size_t)s * D + d];
            float b = Bh[(size_t)s * D + d];
            float sig = 1.f / (1.f + __expf(-(dh + e)));
            num = fmaf(sig, b, num);
            den += sig;
        }
    }
    tmp[(size_t)node * D + d] = Ah[(size_t)node * D + d] + num / (den + 1e-6f);
}

// ---------------------------------------------------------------- batchnorm

__global__ __launch_bounds__(256)
void bn_stats_kernel(const float* __restrict__ tmp, float* __restrict__ stats, int n) {
    const int d = threadIdx.x & 127;
    const int r = threadIdx.x >> 7;  // 0..1
    float s = 0.f, s2 = 0.f;
    for (int row = blockIdx.x * 2 + r; row < n; row += gridDim.x * 2) {
        float v = tmp[(size_t)row * D + d];
        s += v;
        s2 = fmaf(v, v, s2);
    }
    __shared__ float ls[256], ls2[256];
    ls[threadIdx.x] = s; ls2[threadIdx.x] = s2;
    __syncthreads();
    if (r == 0) {
        s  += ls[128 + d];
        s2 += ls2[128 + d];
        atomicAdd(&stats[d], s);
        atomicAdd(&stats[D + d], s2);
    }
}

__global__ __launch_bounds__(256)
void bn_apply_kernel(float* __restrict__ h, const float* __restrict__ tmp,
                     const float* __restrict__ stats,
                     const float* __restrict__ gamma, const float* __restrict__ beta,
                     int n) {
    int i = blockIdx.x * blockDim.x + threadIdx.x;  // over n*32 float4s
    if (i >= n * 32) return;
    const int d0 = (i & 31) * 4;
    const float inv_n = 1.f / (float)n;
    float4 t4 = ((const float4*)tmp)[i];
    float4 h4 = ((float4*)h)[i];
    float tv[4] = {t4.x, t4.y, t4.z, t4.w};
    float hv[4] = {h4.x, h4.y, h4.z, h4.w};
    #pragma unroll
    for (int j = 0; j < 4; ++j) {
        int d = d0 + j;
        float mean = stats[d] * inv_n;
        float var  = stats[D + d] * inv_n - mean * mean;
        float rs   = rsqrtf(var + 1e-5f);
        float v    = gamma[d] * (tv[j] - mean) * rs + beta[d];
        hv[j] += fmaxf(v, 0.f);
    }
    float4 o; o.x = hv[0]; o.y = hv[1]; o.z = hv[2]; o.w = hv[3];
    ((float4*)h)[i] = o;
}

// ---------------------------------------------------------------- readout

__device__ inline int lower_bound_i(const int* a, int n, int key) {
    int lo = 0, hi = n;
    while (lo < hi) {
        int mid = (lo + hi) >> 1;
        if (a[mid] < key) lo = mid + 1; else hi = mid;
    }
    return lo;
}

__global__ __launch_bounds__(128)
void readout_kernel(const float* __restrict__ h, const int* __restrict__ batch,
                    float* __restrict__ hg, int n) {
    const int g = blockIdx.x, d = threadIdx.x;
    const int lo = lower_bound_i(batch, n, g);
    const int hi = lower_bound_i(batch, n, g + 1);
    float s = 0.f;
    for (int i = lo; i < hi; ++i) s += h[(size_t)i * D + d];
    float cnt = (float)(hi - lo);
    hg[g * D + d] = s / fmaxf(cnt, 1.f);
}

__global__ __launch_bounds__(128)
void mlp_kernel(const float* __restrict__ hg,
                const float* __restrict__ w0, const float* __restrict__ b0,
                const float* __restrict__ w1, const float* __restrict__ b1,
                const float* __restrict__ w2, const float* __restrict__ b2,
                float* __restrict__ out) {
    const int g = blockIdx.x, t = threadIdx.x;
    __shared__ float x[128], y[64], z[32];
    x[t] = hg[g * 128 + t];
    __syncthreads();
    if (t < 64) {
        float a = b0[t];
        #pragma unroll 8
        for (int k = 0; k < 128; ++k) a = fmaf(x[k], w0[k * 64 + t], a);
        y[t] = fmaxf(a, 0.f);
    }
    __syncthreads();
    if (t < 32) {
        float a = b1[t];
        #pragma unroll 8
        for (int k = 0; k < 64; ++k) a = fmaf(y[k], w1[k * 32 + t], a);
        z[t] = fmaxf(a, 0.f);
    }
    __syncthreads();
    if (t < 10) {
        float a = b2[t];
        #pragma unroll 8
        for (int k = 0; k < 32; ++k) a = fmaf(z[k], w2[k * 10 + t], a);
        out[g * 10 + t] = a;
    }
}

// ---------------------------------------------------------------- launch

extern "C" void kernel_launch(void* const* d_in, const int* in_sizes, int n_in,
                              void* d_out, int out_size, void* d_ws, size_t ws_size,
                              hipStream_t stream) {
    const float* feature  = (const float*)d_in[0];
    const int*   edge_idx = (const int*)  d_in[1];
    const int*   batch    = (const int*)  d_in[2];
    const float* embed_w  = (const float*)d_in[3];
    const float* embed_b  = (const float*)d_in[4];
    const float* Aw = (const float*)d_in[5];
    const float* Ab = (const float*)d_in[6];
    const float* Bw = (const float*)d_in[7];
    const float* Bb = (const float*)d_in[8];
    const float* Dw = (const float*)d_in[9];
    const float* Db = (const float*)d_in[10];
    const float* Ew = (const float*)d_in[11];
    const float* Eb = (const float*)d_in[12];
    const float* bn_g = (const float*)d_in[13];
    const float* bn_b = (const float*)d_in[14];
    const float* mlp_w0 = (const float*)d_in[15];
    const float* mlp_b0 = (const float*)d_in[16];
    const float* mlp_w1 = (const float*)d_in[17];
    const float* mlp_b1 = (const float*)d_in[18];
    const float* mlp_w2 = (const float*)d_in[19];
    const float* mlp_b2 = (const float*)d_in[20];

    const int N = in_sizes[0] / D;   // 10000
    const int E = in_sizes[1] / 2;   // 640000
    const int L = in_sizes[6] / D;   // 4 (Ab is [L,D])
    const int G = out_size / 10;     // 128

    const int* src = edge_idx;
    const int* dst = edge_idx + E;

    // workspace layout (f32 unless noted)
    size_t NF = (size_t)N * D;
    float* h     = (float*)d_ws;          // [N,D]
    float* Ah    = h + NF;                // [N,D]
    float* Bh    = Ah + NF;               // [N,D]
    float* Dh    = Bh + NF;               // [N,D]
    float* Ehh   = Dh + NF;               // [N,D]
    float* tmp   = Ehh + NF;              // [N,D]
    float* hg    = tmp + NF;              // [G,D]
    float* stats = hg + (size_t)G * D;    // [2,D]
    int* deg      = (int*)(stats + 2 * D);  // [N]
    int* row_ptr  = deg + N;                // [N+1]
    int* fill_ptr = row_ptr + (N + 1);      // [N]
    int* csr_src  = fill_ptr + N;           // [E]

    // ---- CSR by dst (once per call; ws is re-poisoned every call)
    zero_i32_kernel<<<dim3((N + 255) / 256), dim3(256), 0, stream>>>(deg, N);
    count_deg_kernel<<<dim3((E + 255) / 256), dim3(256), 0, stream>>>(dst, deg, E);
    scan_kernel<<<dim3(1), dim3(1024), 0, stream>>>(deg, row_ptr, fill_ptr, N);
    fill_csr_kernel<<<dim3((E + 255) / 256), dim3(256), 0, stream>>>(src, dst, fill_ptr, csr_src, E);

    const int MB = (N + 63) / 64;

    // ---- embedding: h = feature @ embed_w + embed_b
    gemm4_kernel<<<dim3(MB, 1), dim3(256), 0, stream>>>(
        feature,
        embed_w, embed_b, h,  embed_w, embed_b, h,
        embed_w, embed_b, h,  embed_w, embed_b, h, N);

    // ---- GatedGCN layers
    for (int l = 0; l < L; ++l) {
        const float* wA = Aw + (size_t)l * D * D; const float* bA = Ab + (size_t)l * D;
        const float* wB = Bw + (size_t)l * D * D; const float* bB = Bb + (size_t)l * D;
        const float* wD = Dw + (size_t)l * D * D; const float* bD = Db + (size_t)l * D;
        const float* wE = Ew + (size_t)l * D * D; const float* bE = Eb + (size_t)l * D;

        gemm4_kernel<<<dim3(MB, 4), dim3(256), 0, stream>>>(
            h, wA, bA, Ah,  wB, bB, Bh,  wD, bD, Dh,  wE, bE, Ehh, N);

        aggregate_kernel<<<dim3(N), dim3(128), 0, stream>>>(
            Ah, Bh, Dh, Ehh, row_ptr, csr_src, tmp);

        zero_i32_kernel<<<dim3(1), dim3(256), 0, stream>>>((int*)stats, 2 * D);
        bn_stats_kernel<<<dim3(256), dim3(256), 0, stream>>>(tmp, stats, N);
        bn_apply_kernel<<<dim3((N * 32 + 255) / 256), dim3(256), 0, stream>>>(
            h, tmp, stats, bn_g + (size_t)l * D, bn_b + (size_t)l * D, N);
    }

    // ---- readout + MLP
    readout_kernel<<<dim3(G), dim3(128), 0, stream>>>(h, batch, hg, N);
    mlp_kernel<<<dim3(G), dim3(128), 0, stream>>>(
        hg, mlp_w0, mlp_b0, mlp_w1, mlp_b1, mlp_w2, mlp_b2, (float*)d_out);
}